// Round 9
// baseline (4110.822 us; speedup 1.0000x reference)
//
#include <hip/hip_runtime.h>
#include <hip/hip_bf16.h>
#include <math.h>

typedef __bf16 bf16_t;
typedef __bf16 bf16x8 __attribute__((ext_vector_type(8)));
typedef __bf16 bf16x4 __attribute__((ext_vector_type(4)));
typedef float f32x4 __attribute__((ext_vector_type(4)));

// ---------------- np-exact f32 GEMM (encoder) ----------------
// C[M,N] = act(A @ W^T + bias), every C element = single-accumulator
// ascending-k __fmaf_rn chain (replicates BLAS sgemm microkernel semantics),
// bias added with one __fadd_rn after the full chain (np: (x@W.T) + b).
// 128x128 tile, 256 threads, 8x8 per thread. gridDim.y*128==M, K%4==0.
// Zero-padded tails are exact no-ops in the chain (fma(0,0,acc)==acc).
template<int ACT>   // 0 none, 1 relu
__global__ __launch_bounds__(256)
void np_gemm(const float* __restrict__ A, const float* __restrict__ W,
             const float* __restrict__ bias, float* __restrict__ C,
             int N, int K)
{
    __shared__ __align__(16) float sA[16][128];   // [k][m]
    __shared__ __align__(16) float sB[16][128];   // [k][n]
    const int tid  = threadIdx.x;
    const int tx   = tid & 15, ty = tid >> 4;
    const int bRow = blockIdx.y * 128, bCol = blockIdx.x * 128;

    float acc[8][8];
#pragma unroll
    for (int i = 0; i < 8; ++i)
#pragma unroll
        for (int j = 0; j < 8; ++j) acc[i][j] = 0.f;

    for (int k0 = 0; k0 < K; k0 += 16) {
        __syncthreads();
        // stage A,B tiles (128 rows x 16 k) as float4 chunks; K%4==0 so a
        // chunk is fully in or fully out (guard gk<K).
#pragma unroll
        for (int i = 0; i < 2; ++i) {
            int c  = tid + i * 256;        // 0..511
            int r  = c >> 2;               // 0..127
            int kc = (c & 3) << 2;         // 0,4,8,12
            int gk = k0 + kc;
            float4 av = make_float4(0.f, 0.f, 0.f, 0.f);
            float4 bv = make_float4(0.f, 0.f, 0.f, 0.f);
            if (gk < K) av = *(const float4*)(A + (size_t)(bRow + r) * K + gk);
            int gr = bCol + r;
            if (gr < N && gk < K) bv = *(const float4*)(W + (size_t)gr * K + gk);
            sA[kc + 0][r] = av.x; sA[kc + 1][r] = av.y;
            sA[kc + 2][r] = av.z; sA[kc + 3][r] = av.w;
            sB[kc + 0][r] = bv.x; sB[kc + 1][r] = bv.y;
            sB[kc + 2][r] = bv.z; sB[kc + 3][r] = bv.w;
        }
        __syncthreads();

#pragma unroll
        for (int kk = 0; kk < 16; ++kk) {      // strictly ascending k
            float av[8], bv[8];
            *(float4*)&av[0] = *(const float4*)&sA[kk][ty * 8];
            *(float4*)&av[4] = *(const float4*)&sA[kk][ty * 8 + 4];
            *(float4*)&bv[0] = *(const float4*)&sB[kk][tx * 8];
            *(float4*)&bv[4] = *(const float4*)&sB[kk][tx * 8 + 4];
#pragma unroll
            for (int i = 0; i < 8; ++i)
#pragma unroll
                for (int j = 0; j < 8; ++j)
                    acc[i][j] = __fmaf_rn(av[i], bv[j], acc[i][j]);
        }
    }

#pragma unroll
    for (int i = 0; i < 8; ++i) {
        int row = bRow + ty * 8 + i;
#pragma unroll
        for (int j = 0; j < 8; ++j) {
            int col = bCol + tx * 8 + j;
            if (col < N) {
                float v = __fadd_rn(acc[i][j], bias[col]);
                if (ACT == 1) v = v > 0.f ? v : 0.f;
                C[(size_t)row * N + col] = v;
            }
        }
    }
}

// ---------------- bf16-split MFMA GEMM (decoder, 4e-3 slack) ----------------
#define BM 128
#define BN 128
#define BKK 32
// A and W Dekker-split into TERMS bf16 planes; ta+tb<=TERMS-1 accumulated.
// TERMS=2: 3 MFMA, rel err ~2^-17. ACT: 2 leaky(0.1), 3 tanh.
template<int ACT, int TERMS>
__global__ __launch_bounds__(256)
void gemm_bt(const float* __restrict__ A, const float* __restrict__ W,
             const float* __restrict__ bias,
             float* __restrict__ C0, float* __restrict__ C1,
             int N, int K)
{
    __shared__ __align__(16) bf16_t sA[TERMS][BM][BKK];
    __shared__ __align__(16) bf16_t sB[TERMS][BN][BKK];

    const int tid  = threadIdx.x;
    const int bRow = blockIdx.y * BM;
    const int bCol = blockIdx.x * BN;
    const int wave = tid >> 6;
    const int lane = tid & 63;
    const int wr   = (wave >> 1) * 64;
    const int wc   = (wave & 1) * 64;
    const int quad = lane >> 4;
    const int l15  = lane & 15;

    f32x4 acc[4][4];
#pragma unroll
    for (int i = 0; i < 4; ++i)
#pragma unroll
        for (int j = 0; j < 4; ++j) acc[i][j] = (f32x4){0.f, 0.f, 0.f, 0.f};

    for (int k0 = 0; k0 < K; k0 += BKK) {
        __syncthreads();
#pragma unroll
        for (int i = 0; i < 4; ++i) {
            int c   = tid + i * 256;
            int r   = c >> 3;
            int col = (c & 7) << 2;
            int gk  = k0 + col;
            float4 v = make_float4(0.f, 0.f, 0.f, 0.f);
            if (gk < K) v = *(const float4*)(A + (size_t)(bRow + r) * K + gk);
            float e[4] = {v.x, v.y, v.z, v.w};
#pragma unroll
            for (int t = 0; t < TERMS; ++t) {
                bf16x4 hv;
#pragma unroll
                for (int u = 0; u < 4; ++u) {
                    hv[u] = (bf16_t)e[u];
                    e[u] -= (float)hv[u];
                }
                *(bf16x4*)&sA[t][r][col] = hv;
            }
        }
#pragma unroll
        for (int i = 0; i < 4; ++i) {
            int c   = tid + i * 256;
            int r   = c >> 3;
            int col = (c & 7) << 2;
            int gk  = k0 + col;
            int gr  = bCol + r;
            float4 v = make_float4(0.f, 0.f, 0.f, 0.f);
            if (gr < N && gk < K) v = *(const float4*)(W + (size_t)gr * K + gk);
            float e[4] = {v.x, v.y, v.z, v.w};
#pragma unroll
            for (int t = 0; t < TERMS; ++t) {
                bf16x4 hv;
#pragma unroll
                for (int u = 0; u < 4; ++u) {
                    hv[u] = (bf16_t)e[u];
                    e[u] -= (float)hv[u];
                }
                *(bf16x4*)&sB[t][r][col] = hv;
            }
        }
        __syncthreads();

        bf16x8 af[TERMS][4], bfr[TERMS][4];
#pragma unroll
        for (int t = 0; t < TERMS; ++t)
#pragma unroll
            for (int i = 0; i < 4; ++i) {
                af[t][i]  = *(const bf16x8*)&sA[t][wr + i * 16 + l15][quad * 8];
                bfr[t][i] = *(const bf16x8*)&sB[t][wc + i * 16 + l15][quad * 8];
            }
#pragma unroll
        for (int i = 0; i < 4; ++i)
#pragma unroll
            for (int j = 0; j < 4; ++j)
#pragma unroll
                for (int ta = 0; ta < TERMS; ++ta)
#pragma unroll
                    for (int tb = 0; tb < TERMS - ta; ++tb)
                        acc[i][j] = __builtin_amdgcn_mfma_f32_16x16x32_bf16(
                            af[ta][i], bfr[tb][j], acc[i][j], 0, 0, 0);
    }

#pragma unroll
    for (int j = 0; j < 4; ++j) {
        int col = bCol + wc + j * 16 + l15;
        if (col >= N) continue;
        float bv = bias[col];
#pragma unroll
        for (int i = 0; i < 4; ++i) {
#pragma unroll
            for (int r = 0; r < 4; ++r) {
                int row = bRow + wr + i * 16 + quad * 4 + r;
                float v = acc[i][j][r] + bv;
                if (ACT == 1)      v = v > 0.f ? v : 0.f;
                else if (ACT == 2) v = v >= 0.f ? v : 0.1f * v;
                else if (ACT == 3) v = tanhf(v);
                size_t o = (size_t)row * N + col;
                C0[o] = v;
                if (C1) C1[o] = v;
            }
        }
    }
}

// Phase A: per-group top-2 of (cn2[k] - 2 q.c_k), fast f32 (approximate).
__global__ __launch_bounds__(256)
void k_nearest(const float* __restrict__ Q, const float* __restrict__ C,
               const float* __restrict__ cn2, int chunk,
               float* __restrict__ pd, float* __restrict__ pd2, int* __restrict__ pi)
{
    __shared__ __align__(16) float sc[64][64];
    __shared__ __align__(16) float sn[64];
    const int tid = threadIdx.x;
    const int q   = blockIdx.x * 256 + tid;
    const int G   = gridDim.y;

    float qr[64];
    const float4* qp = (const float4*)(Q + (size_t)q * 64);
#pragma unroll
    for (int i = 0; i < 16; ++i) ((float4*)qr)[i] = qp[i];

    float best = 3.4e38f, dsec = 3.4e38f;
    int   bi   = 0;
    const int c0 = blockIdx.y * chunk;

    for (int cb = 0; cb < chunk; cb += 64) {
        __syncthreads();
        const float4* gp = (const float4*)(C + (size_t)(c0 + cb) * 64);
#pragma unroll
        for (int i = 0; i < 4; ++i) {
            int e = tid + i * 256;
            ((float4*)&sc[0][0])[e] = gp[e];
        }
        if (tid < 64) sn[tid] = cn2[c0 + cb + tid];
        __syncthreads();

        for (int c = 0; c < 64; ++c) {
            float d0 = 0.f, d1 = 0.f, d2 = 0.f, d3 = 0.f;
            const float4* ep = (const float4*)&sc[c][0];
#pragma unroll
            for (int z = 0; z < 16; ++z) {
                float4 e4 = ep[z];
                float4 q4 = ((float4*)qr)[z];
                d0 += q4.x * e4.x; d1 += q4.y * e4.y;
                d2 += q4.z * e4.z; d3 += q4.w * e4.w;
            }
            float d = sn[c] - 2.f * ((d0 + d1) + (d2 + d3));
            if (d < best)      { dsec = best; best = d; bi = c0 + cb + c; }
            else if (d < dsec) { dsec = d; }
        }
    }
    pd [(size_t)q * G + blockIdx.y] = best;
    pd2[(size_t)q * G + blockIdx.y] = dsec;
    pi [(size_t)q * G + blockIdx.y] = bi;
}

// Reduce groups; flag gap<2e-3 for np-exact rescan (covers phase-A noise).
__global__ void k_reduce(const float* __restrict__ pd, const float* __restrict__ pd2,
                         const int* __restrict__ pi,
                         int G, int NQ, int* __restrict__ out, int* __restrict__ flag)
{
    int q = blockIdx.x * blockDim.x + threadIdx.x;
    if (q >= NQ) return;
    float best = 3.4e38f, second = 3.4e38f; int bi = 0;
    for (int g = 0; g < G; ++g) {
        float dA = pd [(size_t)q * G + g];
        float dB = pd2[(size_t)q * G + g];
        if (dA < best) {
            second = fminf(fminf(best, dB), second);
            best = dA;
            bi = pi[(size_t)q * G + g];
        } else {
            second = fminf(second, dA);
        }
    }
    out[q]  = bi;
    flag[q] = (second - best) < 2e-3f ? 1 : 0;
}

// np-exact rescan for flagged queries: d = (q2 - 2*dot) + t2 with the dot as
// a single-accumulator ascending-k FMA chain (BLAS sgemm semantics);
// np.argmin first-min (smallest index on exact ties).
__global__ __launch_bounds__(256)
void k_refine_np(const float* __restrict__ Q, const float* __restrict__ C,
                 const float* __restrict__ q2a, const float* __restrict__ t2a,
                 const int* __restrict__ flag, int* __restrict__ idx, int NC)
{
    const int q = blockIdx.x;
    if (!flag[q]) return;
    __shared__ float sq[64];
    __shared__ float sd[256];
    __shared__ int   si[256];
    const int tid = threadIdx.x;
    if (tid < 64) sq[tid] = Q[(size_t)q * 64 + tid];
    __syncthreads();
    const float q2 = q2a[q];
    float best = 3.4e38f; int bi = 0x7fffffff;
    for (int c = tid; c < NC; c += 256) {      // per-thread set ascending
        const float* cp = C + (size_t)c * 64;
        float acc = 0.f;
#pragma unroll
        for (int k = 0; k < 64; ++k)
            acc = __fmaf_rn(sq[k], cp[k], acc);
        float d = __fadd_rn(__fsub_rn(q2, __fmul_rn(2.f, acc)), t2a[c]);
        if (d < best) { best = d; bi = c; }
    }
    sd[tid] = best; si[tid] = bi;
    __syncthreads();
    for (int s = 128; s > 0; s >>= 1) {
        if (tid < s) {
            if (sd[tid + s] < sd[tid] ||
                (sd[tid + s] == sd[tid] && si[tid + s] < si[tid])) {
                sd[tid] = sd[tid + s]; si[tid] = si[tid + s];
            }
        }
        __syncthreads();
    }
    if (tid == 0) idx[q] = si[0];
}

__global__ void k_gather(const float* __restrict__ src, const int* __restrict__ idx,
                         float* __restrict__ dst, int nsrc)
{
    int r = blockIdx.x, z = threadIdx.x;
    int i = idx[r];
    i = i < 0 ? 0 : (i >= nsrc ? nsrc - 1 : i);
    dst[(size_t)r * 64 + z] = src[(size_t)i * 64 + z];
}

// numpy pairwise row norm^2 (n=64): 8 strided accumulators over the rounded
// squares, tree combine ((r0+r1)+(r2+r3))+((r4+r5)+(r6+r7)) — np.sum(x*x,1).
__global__ void k_norm2(const float* __restrict__ s, float* __restrict__ o, int rows)
{
    int r0 = blockIdx.x * blockDim.x + threadIdx.x;
    if (r0 >= rows) return;
    const float* p = s + (size_t)r0 * 64;
    float r[8];
#pragma unroll
    for (int j = 0; j < 8; ++j) r[j] = __fmul_rn(p[j], p[j]);
#pragma unroll
    for (int i = 8; i < 64; i += 8)
#pragma unroll
        for (int j = 0; j < 8; ++j)
            r[j] = __fadd_rn(r[j], __fmul_rn(p[i + j], p[i + j]));
    float t01 = __fadd_rn(r[0], r[1]), t23 = __fadd_rn(r[2], r[3]);
    float t45 = __fadd_rn(r[4], r[5]), t67 = __fadd_rn(r[6], r[7]);
    o[r0] = __fadd_rn(__fadd_rn(t01, t23), __fadd_rn(t45, t67));
}

extern "C" void kernel_launch(void* const* d_in, const int* in_sizes, int n_in,
                              void* d_out, int out_size, void* d_ws, size_t ws_size,
                              hipStream_t stream)
{
    const int B  = 16384;
    const int KC = 4096;
    const int MQ = 4096;   // batch quarter (workspace ~36 MB)

    const float* X   = (const float*)d_in[0];
    const float* We1 = (const float*)d_in[1];
    const float* be1 = (const float*)d_in[2];
    const float* We2 = (const float*)d_in[3];
    const float* be2 = (const float*)d_in[4];
    const float* We3 = (const float*)d_in[5];
    const float* be3 = (const float*)d_in[6];
    const float* We4 = (const float*)d_in[7];
    const float* be4 = (const float*)d_in[8];
    const float* emb = (const float*)d_in[9];
    const float* Wd1 = (const float*)d_in[10];
    const float* bd1 = (const float*)d_in[11];
    const float* Wd2 = (const float*)d_in[12];
    const float* bd2 = (const float*)d_in[13];
    const float* Wd3 = (const float*)d_in[14];
    const float* bd3 = (const float*)d_in[15];
    const float* Wd4 = (const float*)d_in[16];
    const float* bd4 = (const float*)d_in[17];

    float* out = (float*)d_out;
    const size_t OFF1 = (size_t)B * 784;
    const size_t OFF2 = OFF1 + (size_t)B * 64;
    const size_t OFF3 = OFF2 + (size_t)B * 784;
    float* zenc = out + OFF1;

    char* ws = (char*)d_ws;
    size_t off = 0;
    auto alloc = [&](size_t bytes) -> void* {
        void* p = ws + off;
        off = (off + bytes + 255) & ~(size_t)255;
        return p;
    };
    float* pd    = (float*)alloc((size_t)131072 * 4);
    float* pd2   = (float*)alloc((size_t)131072 * 4);
    int*   pi    = (int*)alloc((size_t)131072 * 4);
    int*   idx1  = (int*)alloc((size_t)B * 4);
    int*   idx2  = (int*)alloc((size_t)KC * 4);
    int*   flag1 = (int*)alloc((size_t)B * 4);
    int*   flag2 = (int*)alloc((size_t)KC * 4);
    float* e2    = (float*)alloc((size_t)KC * 4);
    float* z2    = (float*)alloc((size_t)B * 4);
    float* zemb  = (float*)alloc((size_t)B * 64 * 4);
    float* h1    = (float*)alloc((size_t)MQ * 1000 * 4);
    float* h2    = (float*)alloc((size_t)MQ * 500 * 4);
    float* h3    = (float*)alloc((size_t)MQ * 300 * 4);
    float* d1f   = h3;
    float* d2f   = h2;
    float* d3f   = h1;

    dim3 blk(256);
    const dim3 gq1(8, 32), gq2(4, 32), gq3(3, 32), gq4(1, 32), gq5(7, 32);

    // ---- encoder, batch-quartered, np-exact f32 (BLAS-order FMA chains) ----
    for (int q = 0; q < 4; ++q) {
        const float* Xq = X + (size_t)q * MQ * 784;
        np_gemm<1><<<gq1, blk, 0, stream>>>(Xq, We1, be1, h1, 1000, 784);
        np_gemm<1><<<gq2, blk, 0, stream>>>(h1, We2, be2, h2, 500, 1000);
        np_gemm<1><<<gq3, blk, 0, stream>>>(h2, We3, be3, h3, 300, 500);
        np_gemm<0><<<gq4, blk, 0, stream>>>(h3, We4, be4,
                                            zenc + (size_t)q * MQ * 64, 64, 300);
    }

    // ---- nearest-neighbor: f32 phase A + np-exact refine on flagged ----
    k_norm2<<<dim3((KC + 255) / 256), blk, 0, stream>>>(emb, e2, KC);
    k_norm2<<<dim3((B + 255) / 256),  blk, 0, stream>>>(zenc, z2, B);

    k_nearest  <<<dim3(64, 8),  blk, 0, stream>>>(zenc, emb, e2, 512, pd, pd2, pi);
    k_reduce   <<<dim3(B / 256), blk, 0, stream>>>(pd, pd2, pi, 8, B, idx1, flag1);
    k_refine_np<<<dim3(B), blk, 0, stream>>>(zenc, emb, z2, e2, flag1, idx1, KC);
    k_gather   <<<dim3(B), dim3(64), 0, stream>>>(emb, idx1, zemb, KC);

    k_nearest  <<<dim3(16, 32), blk, 0, stream>>>(emb, zenc, z2, 512, pd, pd2, pi);
    k_reduce   <<<dim3(KC / 256), blk, 0, stream>>>(pd, pd2, pi, 32, KC, idx2, flag2);
    k_refine_np<<<dim3(KC), blk, 0, stream>>>(emb, zenc, e2, z2, flag2, idx2, B);
    k_gather   <<<dim3(KC), dim3(64), 0, stream>>>(zenc, idx2, out + OFF3, B);

    // ---- decoder, batch-quartered; TERMS=2 bf16-split MFMA (4e-3 slack) ----
    for (int q = 0; q < 4; ++q) {
        const float* zq = zemb + (size_t)q * MQ * 64;
        gemm_bt<2, 2><<<gq3, blk, 0, stream>>>(zq,  Wd1, bd1, d1f, nullptr, 300,  64);
        gemm_bt<2, 2><<<gq2, blk, 0, stream>>>(d1f, Wd2, bd2, d2f, nullptr, 500,  300);
        gemm_bt<2, 2><<<gq1, blk, 0, stream>>>(d2f, Wd3, bd3, d3f, nullptr, 1000, 500);
        gemm_bt<3, 2><<<gq5, blk, 0, stream>>>(d3f, Wd4, bd4,
                                               out + (size_t)q * MQ * 784,
                                               out + OFF2 + (size_t)q * MQ * 784, 784, 1000);
    }

    (void)in_sizes; (void)n_in; (void)out_size; (void)ws_size;
}

// Round 10
// 3442.113 us; speedup vs baseline: 1.1943x; 1.1943x over previous
//
#include <hip/hip_runtime.h>
#include <hip/hip_bf16.h>
#include <math.h>

typedef __bf16 bf16_t;
typedef __bf16 bf16x8 __attribute__((ext_vector_type(8)));
typedef __bf16 bf16x4 __attribute__((ext_vector_type(4)));
typedef float f32x4 __attribute__((ext_vector_type(4)));

// ---------------- np-exact f32 GEMM (encoder) ----------------
// C[M,N] = act(A @ W^T + bias), every C element = single-accumulator
// ascending-k __fmaf_rn chain (replicates BLAS sgemm microkernel semantics),
// bias added with one __fadd_rn after the full chain (np: (x@W.T) + b).
// 128x128 tile, 256 threads, 8x8 per thread. gridDim.y*128==M, K%4==0.
template<int ACT>   // 0 none, 1 relu
__global__ __launch_bounds__(256)
void np_gemm(const float* __restrict__ A, const float* __restrict__ W,
             const float* __restrict__ bias, float* __restrict__ C,
             int N, int K)
{
    __shared__ __align__(16) float sA[16][128];   // [k][m]
    __shared__ __align__(16) float sB[16][128];   // [k][n]
    const int tid  = threadIdx.x;
    const int tx   = tid & 15, ty = tid >> 4;
    const int bRow = blockIdx.y * 128, bCol = blockIdx.x * 128;

    float acc[8][8];
#pragma unroll
    for (int i = 0; i < 8; ++i)
#pragma unroll
        for (int j = 0; j < 8; ++j) acc[i][j] = 0.f;

    for (int k0 = 0; k0 < K; k0 += 16) {
        __syncthreads();
#pragma unroll
        for (int i = 0; i < 2; ++i) {
            int c  = tid + i * 256;        // 0..511
            int r  = c >> 2;               // 0..127
            int kc = (c & 3) << 2;         // 0,4,8,12
            int gk = k0 + kc;
            float4 av = make_float4(0.f, 0.f, 0.f, 0.f);
            float4 bv = make_float4(0.f, 0.f, 0.f, 0.f);
            if (gk < K) av = *(const float4*)(A + (size_t)(bRow + r) * K + gk);
            int gr = bCol + r;
            if (gr < N && gk < K) bv = *(const float4*)(W + (size_t)gr * K + gk);
            sA[kc + 0][r] = av.x; sA[kc + 1][r] = av.y;
            sA[kc + 2][r] = av.z; sA[kc + 3][r] = av.w;
            sB[kc + 0][r] = bv.x; sB[kc + 1][r] = bv.y;
            sB[kc + 2][r] = bv.z; sB[kc + 3][r] = bv.w;
        }
        __syncthreads();

#pragma unroll
        for (int kk = 0; kk < 16; ++kk) {      // strictly ascending k
            float av[8], bv[8];
            *(float4*)&av[0] = *(const float4*)&sA[kk][ty * 8];
            *(float4*)&av[4] = *(const float4*)&sA[kk][ty * 8 + 4];
            *(float4*)&bv[0] = *(const float4*)&sB[kk][tx * 8];
            *(float4*)&bv[4] = *(const float4*)&sB[kk][tx * 8 + 4];
#pragma unroll
            for (int i = 0; i < 8; ++i)
#pragma unroll
                for (int j = 0; j < 8; ++j)
                    acc[i][j] = __fmaf_rn(av[i], bv[j], acc[i][j]);
        }
    }

#pragma unroll
    for (int i = 0; i < 8; ++i) {
        int row = bRow + ty * 8 + i;
#pragma unroll
        for (int j = 0; j < 8; ++j) {
            int col = bCol + tx * 8 + j;
            if (col < N) {
                float v = __fadd_rn(acc[i][j], bias[col]);
                if (ACT == 1) v = v > 0.f ? v : 0.f;
                C[(size_t)row * N + col] = v;
            }
        }
    }
}

// ---------------- bf16-split MFMA GEMM (decoder, 4e-3 slack) ----------------
#define BM 128
#define BN 128
#define BKK 32
template<int ACT, int TERMS>
__global__ __launch_bounds__(256)
void gemm_bt(const float* __restrict__ A, const float* __restrict__ W,
             const float* __restrict__ bias,
             float* __restrict__ C0, float* __restrict__ C1,
             int N, int K)
{
    __shared__ __align__(16) bf16_t sA[TERMS][BM][BKK];
    __shared__ __align__(16) bf16_t sB[TERMS][BN][BKK];

    const int tid  = threadIdx.x;
    const int bRow = blockIdx.y * BM;
    const int bCol = blockIdx.x * BN;
    const int wave = tid >> 6;
    const int lane = tid & 63;
    const int wr   = (wave >> 1) * 64;
    const int wc   = (wave & 1) * 64;
    const int quad = lane >> 4;
    const int l15  = lane & 15;

    f32x4 acc[4][4];
#pragma unroll
    for (int i = 0; i < 4; ++i)
#pragma unroll
        for (int j = 0; j < 4; ++j) acc[i][j] = (f32x4){0.f, 0.f, 0.f, 0.f};

    for (int k0 = 0; k0 < K; k0 += BKK) {
        __syncthreads();
#pragma unroll
        for (int i = 0; i < 4; ++i) {
            int c   = tid + i * 256;
            int r   = c >> 3;
            int col = (c & 7) << 2;
            int gk  = k0 + col;
            float4 v = make_float4(0.f, 0.f, 0.f, 0.f);
            if (gk < K) v = *(const float4*)(A + (size_t)(bRow + r) * K + gk);
            float e[4] = {v.x, v.y, v.z, v.w};
#pragma unroll
            for (int t = 0; t < TERMS; ++t) {
                bf16x4 hv;
#pragma unroll
                for (int u = 0; u < 4; ++u) {
                    hv[u] = (bf16_t)e[u];
                    e[u] -= (float)hv[u];
                }
                *(bf16x4*)&sA[t][r][col] = hv;
            }
        }
#pragma unroll
        for (int i = 0; i < 4; ++i) {
            int c   = tid + i * 256;
            int r   = c >> 3;
            int col = (c & 7) << 2;
            int gk  = k0 + col;
            int gr  = bCol + r;
            float4 v = make_float4(0.f, 0.f, 0.f, 0.f);
            if (gr < N && gk < K) v = *(const float4*)(W + (size_t)gr * K + gk);
            float e[4] = {v.x, v.y, v.z, v.w};
#pragma unroll
            for (int t = 0; t < TERMS; ++t) {
                bf16x4 hv;
#pragma unroll
                for (int u = 0; u < 4; ++u) {
                    hv[u] = (bf16_t)e[u];
                    e[u] -= (float)hv[u];
                }
                *(bf16x4*)&sB[t][r][col] = hv;
            }
        }
        __syncthreads();

        bf16x8 af[TERMS][4], bfr[TERMS][4];
#pragma unroll
        for (int t = 0; t < TERMS; ++t)
#pragma unroll
            for (int i = 0; i < 4; ++i) {
                af[t][i]  = *(const bf16x8*)&sA[t][wr + i * 16 + l15][quad * 8];
                bfr[t][i] = *(const bf16x8*)&sB[t][wc + i * 16 + l15][quad * 8];
            }
#pragma unroll
        for (int i = 0; i < 4; ++i)
#pragma unroll
            for (int j = 0; j < 4; ++j)
#pragma unroll
                for (int ta = 0; ta < TERMS; ++ta)
#pragma unroll
                    for (int tb = 0; tb < TERMS - ta; ++tb)
                        acc[i][j] = __builtin_amdgcn_mfma_f32_16x16x32_bf16(
                            af[ta][i], bfr[tb][j], acc[i][j], 0, 0, 0);
    }

#pragma unroll
    for (int j = 0; j < 4; ++j) {
        int col = bCol + wc + j * 16 + l15;
        if (col >= N) continue;
        float bv = bias[col];
#pragma unroll
        for (int i = 0; i < 4; ++i) {
#pragma unroll
            for (int r = 0; r < 4; ++r) {
                int row = bRow + wr + i * 16 + quad * 4 + r;
                float v = acc[i][j][r] + bv;
                if (ACT == 1)      v = v > 0.f ? v : 0.f;
                else if (ACT == 2) v = v >= 0.f ? v : 0.1f * v;
                else if (ACT == 3) v = tanhf(v);
                size_t o = (size_t)row * N + col;
                C0[o] = v;
                if (C1) C1[o] = v;
            }
        }
    }
}

// np-exact nearest scan: one query/thread, candidates LDS-staged 64 at a
// time (wave-uniform broadcast reads). Per candidate: single-accumulator
// ascending-k FMA chain; d = fl(fl(q2 - fl(2*dot)) + t2); strict-< first-min
// over ascending candidate indices => bit-identical to the np reference.
// 4 candidates in flight for ILP (chains independent across candidates).
__global__ __launch_bounds__(256)
void k_nearest(const float* __restrict__ Q, const float* __restrict__ C,
               const float* __restrict__ q2a, const float* __restrict__ cn2,
               int chunk, float* __restrict__ pd, int* __restrict__ pi)
{
    __shared__ __align__(16) float sc[64][64];
    __shared__ __align__(16) float sn[64];
    const int tid = threadIdx.x;
    const int q   = blockIdx.x * 256 + tid;
    const int G   = gridDim.y;

    float qr[64];
    const float4* qp = (const float4*)(Q + (size_t)q * 64);
#pragma unroll
    for (int i = 0; i < 16; ++i) ((float4*)qr)[i] = qp[i];
    const float q2 = q2a[q];

    float best = 3.4e38f;
    int   bi   = 0x7fffffff;
    const int c0 = blockIdx.y * chunk;

    for (int cb = 0; cb < chunk; cb += 64) {
        __syncthreads();
        const float4* gp = (const float4*)(C + (size_t)(c0 + cb) * 64);
#pragma unroll
        for (int i = 0; i < 4; ++i) {
            int e = tid + i * 256;
            ((float4*)&sc[0][0])[e] = gp[e];
        }
        if (tid < 64) sn[tid] = cn2[c0 + cb + tid];
        __syncthreads();

        for (int c = 0; c < 64; c += 4) {
            float a0 = 0.f, a1 = 0.f, a2 = 0.f, a3 = 0.f;
            const float4* e0 = (const float4*)&sc[c + 0][0];
            const float4* e1 = (const float4*)&sc[c + 1][0];
            const float4* e2p = (const float4*)&sc[c + 2][0];
            const float4* e3 = (const float4*)&sc[c + 3][0];
#pragma unroll
            for (int z = 0; z < 16; ++z) {          // k ascending, chain order exact
                float4 q4 = ((float4*)qr)[z];
                float4 v0 = e0[z], v1 = e1[z], v2 = e2p[z], v3 = e3[z];
                a0 = __fmaf_rn(q4.x, v0.x, a0); a0 = __fmaf_rn(q4.y, v0.y, a0);
                a0 = __fmaf_rn(q4.z, v0.z, a0); a0 = __fmaf_rn(q4.w, v0.w, a0);
                a1 = __fmaf_rn(q4.x, v1.x, a1); a1 = __fmaf_rn(q4.y, v1.y, a1);
                a1 = __fmaf_rn(q4.z, v1.z, a1); a1 = __fmaf_rn(q4.w, v1.w, a1);
                a2 = __fmaf_rn(q4.x, v2.x, a2); a2 = __fmaf_rn(q4.y, v2.y, a2);
                a2 = __fmaf_rn(q4.z, v2.z, a2); a2 = __fmaf_rn(q4.w, v2.w, a2);
                a3 = __fmaf_rn(q4.x, v3.x, a3); a3 = __fmaf_rn(q4.y, v3.y, a3);
                a3 = __fmaf_rn(q4.z, v3.z, a3); a3 = __fmaf_rn(q4.w, v3.w, a3);
            }
            float d;
            d = __fadd_rn(__fsub_rn(q2, __fmul_rn(2.f, a0)), sn[c + 0]);
            if (d < best) { best = d; bi = c0 + cb + c + 0; }
            d = __fadd_rn(__fsub_rn(q2, __fmul_rn(2.f, a1)), sn[c + 1]);
            if (d < best) { best = d; bi = c0 + cb + c + 1; }
            d = __fadd_rn(__fsub_rn(q2, __fmul_rn(2.f, a2)), sn[c + 2]);
            if (d < best) { best = d; bi = c0 + cb + c + 2; }
            d = __fadd_rn(__fsub_rn(q2, __fmul_rn(2.f, a3)), sn[c + 3]);
            if (d < best) { best = d; bi = c0 + cb + c + 3; }
        }
    }
    pd[(size_t)q * G + blockIdx.y] = best;
    pi[(size_t)q * G + blockIdx.y] = bi;
}

// Reduce groups: groups are ascending index ranges, strict-< keeps the
// earliest group's min on exact ties => np.argmin first-min semantics.
__global__ void k_reduce(const float* __restrict__ pd, const int* __restrict__ pi,
                         int G, int NQ, int* __restrict__ out)
{
    int q = blockIdx.x * blockDim.x + threadIdx.x;
    if (q >= NQ) return;
    float best = 3.4e38f; int bi = 0;
    for (int g = 0; g < G; ++g) {
        float d = pd[(size_t)q * G + g];
        if (d < best) { best = d; bi = pi[(size_t)q * G + g]; }
    }
    out[q] = bi;
}

__global__ void k_gather(const float* __restrict__ src, const int* __restrict__ idx,
                         float* __restrict__ dst, int nsrc)
{
    int r = blockIdx.x, z = threadIdx.x;
    int i = idx[r];
    i = i < 0 ? 0 : (i >= nsrc ? nsrc - 1 : i);
    dst[(size_t)r * 64 + z] = src[(size_t)i * 64 + z];
}

// numpy pairwise row norm^2 (n=64): 8 strided accumulators over rounded
// squares, tree combine — np.sum(x*x, axis=1) bit-exact.
__global__ void k_norm2(const float* __restrict__ s, float* __restrict__ o, int rows)
{
    int r0 = blockIdx.x * blockDim.x + threadIdx.x;
    if (r0 >= rows) return;
    const float* p = s + (size_t)r0 * 64;
    float r[8];
#pragma unroll
    for (int j = 0; j < 8; ++j) r[j] = __fmul_rn(p[j], p[j]);
#pragma unroll
    for (int i = 8; i < 64; i += 8)
#pragma unroll
        for (int j = 0; j < 8; ++j)
            r[j] = __fadd_rn(r[j], __fmul_rn(p[i + j], p[i + j]));
    float t01 = __fadd_rn(r[0], r[1]), t23 = __fadd_rn(r[2], r[3]);
    float t45 = __fadd_rn(r[4], r[5]), t67 = __fadd_rn(r[6], r[7]);
    o[r0] = __fadd_rn(__fadd_rn(t01, t23), __fadd_rn(t45, t67));
}

extern "C" void kernel_launch(void* const* d_in, const int* in_sizes, int n_in,
                              void* d_out, int out_size, void* d_ws, size_t ws_size,
                              hipStream_t stream)
{
    const int B  = 16384;
    const int KC = 4096;
    const int MQ = 4096;   // batch quarter (workspace ~36 MB)

    const float* X   = (const float*)d_in[0];
    const float* We1 = (const float*)d_in[1];
    const float* be1 = (const float*)d_in[2];
    const float* We2 = (const float*)d_in[3];
    const float* be2 = (const float*)d_in[4];
    const float* We3 = (const float*)d_in[5];
    const float* be3 = (const float*)d_in[6];
    const float* We4 = (const float*)d_in[7];
    const float* be4 = (const float*)d_in[8];
    const float* emb = (const float*)d_in[9];
    const float* Wd1 = (const float*)d_in[10];
    const float* bd1 = (const float*)d_in[11];
    const float* Wd2 = (const float*)d_in[12];
    const float* bd2 = (const float*)d_in[13];
    const float* Wd3 = (const float*)d_in[14];
    const float* bd3 = (const float*)d_in[15];
    const float* Wd4 = (const float*)d_in[16];
    const float* bd4 = (const float*)d_in[17];

    float* out = (float*)d_out;
    const size_t OFF1 = (size_t)B * 784;
    const size_t OFF2 = OFF1 + (size_t)B * 64;
    const size_t OFF3 = OFF2 + (size_t)B * 784;
    float* zenc = out + OFF1;

    char* ws = (char*)d_ws;
    size_t off = 0;
    auto alloc = [&](size_t bytes) -> void* {
        void* p = ws + off;
        off = (off + bytes + 255) & ~(size_t)255;
        return p;
    };
    float* pd    = (float*)alloc((size_t)262144 * 4);
    int*   pi    = (int*)alloc((size_t)262144 * 4);
    int*   idx1  = (int*)alloc((size_t)B * 4);
    int*   idx2  = (int*)alloc((size_t)KC * 4);
    float* e2    = (float*)alloc((size_t)KC * 4);
    float* z2    = (float*)alloc((size_t)B * 4);
    float* zemb  = (float*)alloc((size_t)B * 64 * 4);
    float* h1    = (float*)alloc((size_t)MQ * 1000 * 4);
    float* h2    = (float*)alloc((size_t)MQ * 500 * 4);
    float* h3    = (float*)alloc((size_t)MQ * 300 * 4);
    float* d1f   = h3;
    float* d2f   = h2;
    float* d3f   = h1;

    dim3 blk(256);
    const dim3 gq1(8, 32), gq2(4, 32), gq3(3, 32), gq4(1, 32), gq5(7, 32);

    // ---- encoder, batch-quartered, np-exact f32 (BLAS-order FMA chains) ----
    for (int q = 0; q < 4; ++q) {
        const float* Xq = X + (size_t)q * MQ * 784;
        np_gemm<1><<<gq1, blk, 0, stream>>>(Xq, We1, be1, h1, 1000, 784);
        np_gemm<1><<<gq2, blk, 0, stream>>>(h1, We2, be2, h2, 500, 1000);
        np_gemm<1><<<gq3, blk, 0, stream>>>(h2, We3, be3, h3, 300, 500);
        np_gemm<0><<<gq4, blk, 0, stream>>>(h3, We4, be4,
                                            zenc + (size_t)q * MQ * 64, 64, 300);
    }

    // ---- nearest-neighbor: np-exact phase A, no refine needed ----
    k_norm2<<<dim3((KC + 255) / 256), blk, 0, stream>>>(emb, e2, KC);
    k_norm2<<<dim3((B + 255) / 256),  blk, 0, stream>>>(zenc, z2, B);

    // nearest1: B queries vs KC codes (grid 64 x 16, chunk 256)
    k_nearest<<<dim3(64, 16), blk, 0, stream>>>(zenc, emb, z2, e2, 256, pd, pi);
    k_reduce <<<dim3(B / 256), blk, 0, stream>>>(pd, pi, 16, B, idx1);
    k_gather <<<dim3(B), dim3(64), 0, stream>>>(emb, idx1, zemb, KC);

    // nearest2: KC codes vs B encodings (grid 16 x 64, chunk 256)
    k_nearest<<<dim3(16, 64), blk, 0, stream>>>(emb, zenc, e2, z2, 256, pd, pi);
    k_reduce <<<dim3(KC / 256), blk, 0, stream>>>(pd, pi, 64, KC, idx2);
    k_gather <<<dim3(KC), dim3(64), 0, stream>>>(zenc, idx2, out + OFF3, B);

    // ---- decoder, batch-quartered; TERMS=2 bf16-split MFMA (4e-3 slack) ----
    for (int q = 0; q < 4; ++q) {
        const float* zq = zemb + (size_t)q * MQ * 64;
        gemm_bt<2, 2><<<gq3, blk, 0, stream>>>(zq,  Wd1, bd1, d1f, nullptr, 300,  64);
        gemm_bt<2, 2><<<gq2, blk, 0, stream>>>(d1f, Wd2, bd2, d2f, nullptr, 500,  300);
        gemm_bt<2, 2><<<gq1, blk, 0, stream>>>(d2f, Wd3, bd3, d3f, nullptr, 1000, 500);
        gemm_bt<3, 2><<<gq5, blk, 0, stream>>>(d3f, Wd4, bd4,
                                               out + (size_t)q * MQ * 784,
                                               out + OFF2 + (size_t)q * MQ * 784, 784, 1000);
    }

    (void)in_sizes; (void)n_in; (void)out_size; (void)ws_size;
}

// Round 11
// 1628.032 us; speedup vs baseline: 2.5250x; 2.1143x over previous
//
#include <hip/hip_runtime.h>
#include <hip/hip_bf16.h>
#include <math.h>

typedef __bf16 bf16_t;
typedef __bf16 bf16x8 __attribute__((ext_vector_type(8)));
typedef __bf16 bf16x4 __attribute__((ext_vector_type(4)));
typedef float f32x4 __attribute__((ext_vector_type(4)));

// ---------------- np-exact f32 GEMM (encoder) ----------------
// C[M,N] = act(A @ W^T + bias). Each C element = single-accumulator
// ascending-k __fmaf_rn chain (BLAS sgemm semantics), one __fadd_rn bias.
// Tile: (RB*64) x 128, 256 threads, thread (tx,ty) owns rows
// {ib*64+ty*4+i} and cols {jb*64+tx*4+j} -> sB reads are 2-way (free) on
// LDS banks instead of 4-way. gridDim.y*RB*64 == M, K%4==0, N%4==0.
template<int ACT, int RB>   // ACT: 0 none, 1 relu;  BM = RB*64
__global__ __launch_bounds__(256)
void np_gemm(const float* __restrict__ A, const float* __restrict__ W,
             const float* __restrict__ bias, float* __restrict__ C,
             int N, int K)
{
    __shared__ __align__(16) float sA[16][RB * 64];   // [k][m]
    __shared__ __align__(16) float sB[16][128];       // [k][n]
    const int tid  = threadIdx.x;
    const int tx   = tid & 15, ty = tid >> 4;
    const int bRow = blockIdx.y * (RB * 64), bCol = blockIdx.x * 128;

    float4 acc[RB][2][4];
#pragma unroll
    for (int ib = 0; ib < RB; ++ib)
#pragma unroll
        for (int jb = 0; jb < 2; ++jb)
#pragma unroll
            for (int i = 0; i < 4; ++i)
                acc[ib][jb][i] = make_float4(0.f, 0.f, 0.f, 0.f);

    for (int k0 = 0; k0 < K; k0 += 16) {
        __syncthreads();
        // stage A tile (RB*64 rows x 16 k): RB*256 float4 chunks
#pragma unroll
        for (int i = 0; i < RB; ++i) {
            int c  = tid + i * 256;
            int r  = c >> 2;
            int kc = (c & 3) << 2;
            int gk = k0 + kc;
            float4 av = make_float4(0.f, 0.f, 0.f, 0.f);
            if (gk < K) av = *(const float4*)(A + (size_t)(bRow + r) * K + gk);
            sA[kc + 0][r] = av.x; sA[kc + 1][r] = av.y;
            sA[kc + 2][r] = av.z; sA[kc + 3][r] = av.w;
        }
        // stage B tile (128 rows x 16 k): 512 float4 chunks
#pragma unroll
        for (int i = 0; i < 2; ++i) {
            int c  = tid + i * 256;
            int r  = c >> 2;
            int kc = (c & 3) << 2;
            int gk = k0 + kc;
            int gr = bCol + r;
            float4 bv = make_float4(0.f, 0.f, 0.f, 0.f);
            if (gr < N && gk < K) bv = *(const float4*)(W + (size_t)gr * K + gk);
            sB[kc + 0][r] = bv.x; sB[kc + 1][r] = bv.y;
            sB[kc + 2][r] = bv.z; sB[kc + 3][r] = bv.w;
        }
        __syncthreads();

#pragma unroll
        for (int kk = 0; kk < 16; ++kk) {      // strictly ascending k
            float4 a[RB], b[2];
#pragma unroll
            for (int ib = 0; ib < RB; ++ib)
                a[ib] = *(const float4*)&sA[kk][ib * 64 + ty * 4];
            b[0] = *(const float4*)&sB[kk][tx * 4];
            b[1] = *(const float4*)&sB[kk][64 + tx * 4];
#pragma unroll
            for (int ib = 0; ib < RB; ++ib) {
                float ai[4] = {a[ib].x, a[ib].y, a[ib].z, a[ib].w};
#pragma unroll
                for (int i = 0; i < 4; ++i)
#pragma unroll
                    for (int jb = 0; jb < 2; ++jb) {
                        acc[ib][jb][i].x = __fmaf_rn(ai[i], b[jb].x, acc[ib][jb][i].x);
                        acc[ib][jb][i].y = __fmaf_rn(ai[i], b[jb].y, acc[ib][jb][i].y);
                        acc[ib][jb][i].z = __fmaf_rn(ai[i], b[jb].z, acc[ib][jb][i].z);
                        acc[ib][jb][i].w = __fmaf_rn(ai[i], b[jb].w, acc[ib][jb][i].w);
                    }
            }
        }
    }

#pragma unroll
    for (int jb = 0; jb < 2; ++jb) {
        int col = bCol + jb * 64 + tx * 4;
        if (col >= N) continue;                 // N%4==0 -> whole float4 in bounds
        float4 bb = *(const float4*)(bias + col);
#pragma unroll
        for (int ib = 0; ib < RB; ++ib)
#pragma unroll
            for (int i = 0; i < 4; ++i) {
                int row = bRow + ib * 64 + ty * 4 + i;
                float4 v = acc[ib][jb][i];
                float4 o;
                o.x = __fadd_rn(v.x, bb.x); o.y = __fadd_rn(v.y, bb.y);
                o.z = __fadd_rn(v.z, bb.z); o.w = __fadd_rn(v.w, bb.w);
                if (ACT == 1) {
                    o.x = o.x > 0.f ? o.x : 0.f; o.y = o.y > 0.f ? o.y : 0.f;
                    o.z = o.z > 0.f ? o.z : 0.f; o.w = o.w > 0.f ? o.w : 0.f;
                }
                *(float4*)(C + (size_t)row * N + col) = o;
            }
    }
}

// ---------------- bf16-split MFMA GEMM (decoder, 4e-3 slack) ----------------
#define BM 128
#define BN 128
#define BKK 32
template<int ACT, int TERMS>
__global__ __launch_bounds__(256)
void gemm_bt(const float* __restrict__ A, const float* __restrict__ W,
             const float* __restrict__ bias,
             float* __restrict__ C0, float* __restrict__ C1,
             int N, int K)
{
    __shared__ __align__(16) bf16_t sA[TERMS][BM][BKK];
    __shared__ __align__(16) bf16_t sB[TERMS][BN][BKK];

    const int tid  = threadIdx.x;
    const int bRow = blockIdx.y * BM;
    const int bCol = blockIdx.x * BN;
    const int wave = tid >> 6;
    const int lane = tid & 63;
    const int wr   = (wave >> 1) * 64;
    const int wc   = (wave & 1) * 64;
    const int quad = lane >> 4;
    const int l15  = lane & 15;

    f32x4 acc[4][4];
#pragma unroll
    for (int i = 0; i < 4; ++i)
#pragma unroll
        for (int j = 0; j < 4; ++j) acc[i][j] = (f32x4){0.f, 0.f, 0.f, 0.f};

    for (int k0 = 0; k0 < K; k0 += BKK) {
        __syncthreads();
#pragma unroll
        for (int i = 0; i < 4; ++i) {
            int c   = tid + i * 256;
            int r   = c >> 3;
            int col = (c & 7) << 2;
            int gk  = k0 + col;
            float4 v = make_float4(0.f, 0.f, 0.f, 0.f);
            if (gk < K) v = *(const float4*)(A + (size_t)(bRow + r) * K + gk);
            float e[4] = {v.x, v.y, v.z, v.w};
#pragma unroll
            for (int t = 0; t < TERMS; ++t) {
                bf16x4 hv;
#pragma unroll
                for (int u = 0; u < 4; ++u) {
                    hv[u] = (bf16_t)e[u];
                    e[u] -= (float)hv[u];
                }
                *(bf16x4*)&sA[t][r][col] = hv;
            }
        }
#pragma unroll
        for (int i = 0; i < 4; ++i) {
            int c   = tid + i * 256;
            int r   = c >> 3;
            int col = (c & 7) << 2;
            int gk  = k0 + col;
            int gr  = bCol + r;
            float4 v = make_float4(0.f, 0.f, 0.f, 0.f);
            if (gr < N && gk < K) v = *(const float4*)(W + (size_t)gr * K + gk);
            float e[4] = {v.x, v.y, v.z, v.w};
#pragma unroll
            for (int t = 0; t < TERMS; ++t) {
                bf16x4 hv;
#pragma unroll
                for (int u = 0; u < 4; ++u) {
                    hv[u] = (bf16_t)e[u];
                    e[u] -= (float)hv[u];
                }
                *(bf16x4*)&sB[t][r][col] = hv;
            }
        }
        __syncthreads();

        bf16x8 af[TERMS][4], bfr[TERMS][4];
#pragma unroll
        for (int t = 0; t < TERMS; ++t)
#pragma unroll
            for (int i = 0; i < 4; ++i) {
                af[t][i]  = *(const bf16x8*)&sA[t][wr + i * 16 + l15][quad * 8];
                bfr[t][i] = *(const bf16x8*)&sB[t][wc + i * 16 + l15][quad * 8];
            }
#pragma unroll
        for (int i = 0; i < 4; ++i)
#pragma unroll
            for (int j = 0; j < 4; ++j)
#pragma unroll
                for (int ta = 0; ta < TERMS; ++ta)
#pragma unroll
                    for (int tb = 0; tb < TERMS - ta; ++tb)
                        acc[i][j] = __builtin_amdgcn_mfma_f32_16x16x32_bf16(
                            af[ta][i], bfr[tb][j], acc[i][j], 0, 0, 0);
    }

#pragma unroll
    for (int j = 0; j < 4; ++j) {
        int col = bCol + wc + j * 16 + l15;
        if (col >= N) continue;
        float bv = bias[col];
#pragma unroll
        for (int i = 0; i < 4; ++i) {
#pragma unroll
            for (int r = 0; r < 4; ++r) {
                int row = bRow + wr + i * 16 + quad * 4 + r;
                float v = acc[i][j][r] + bv;
                if (ACT == 1)      v = v > 0.f ? v : 0.f;
                else if (ACT == 2) v = v >= 0.f ? v : 0.1f * v;
                else if (ACT == 3) v = tanhf(v);
                size_t o = (size_t)row * N + col;
                C0[o] = v;
                if (C1) C1[o] = v;
            }
        }
    }
}

// np-exact nearest scan (bit-identical to np reference; see round 10).
__global__ __launch_bounds__(256)
void k_nearest(const float* __restrict__ Q, const float* __restrict__ C,
               const float* __restrict__ q2a, const float* __restrict__ cn2,
               int chunk, float* __restrict__ pd, int* __restrict__ pi)
{
    __shared__ __align__(16) float sc[64][64];
    __shared__ __align__(16) float sn[64];
    const int tid = threadIdx.x;
    const int q   = blockIdx.x * 256 + tid;
    const int G   = gridDim.y;

    float qr[64];
    const float4* qp = (const float4*)(Q + (size_t)q * 64);
#pragma unroll
    for (int i = 0; i < 16; ++i) ((float4*)qr)[i] = qp[i];
    const float q2 = q2a[q];

    float best = 3.4e38f;
    int   bi   = 0x7fffffff;
    const int c0 = blockIdx.y * chunk;

    for (int cb = 0; cb < chunk; cb += 64) {
        __syncthreads();
        const float4* gp = (const float4*)(C + (size_t)(c0 + cb) * 64);
#pragma unroll
        for (int i = 0; i < 4; ++i) {
            int e = tid + i * 256;
            ((float4*)&sc[0][0])[e] = gp[e];
        }
        if (tid < 64) sn[tid] = cn2[c0 + cb + tid];
        __syncthreads();

        for (int c = 0; c < 64; c += 4) {
            float a0 = 0.f, a1 = 0.f, a2 = 0.f, a3 = 0.f;
            const float4* e0 = (const float4*)&sc[c + 0][0];
            const float4* e1 = (const float4*)&sc[c + 1][0];
            const float4* e2p = (const float4*)&sc[c + 2][0];
            const float4* e3 = (const float4*)&sc[c + 3][0];
#pragma unroll
            for (int z = 0; z < 16; ++z) {          // k ascending, chain order exact
                float4 q4 = ((float4*)qr)[z];
                float4 v0 = e0[z], v1 = e1[z], v2 = e2p[z], v3 = e3[z];
                a0 = __fmaf_rn(q4.x, v0.x, a0); a0 = __fmaf_rn(q4.y, v0.y, a0);
                a0 = __fmaf_rn(q4.z, v0.z, a0); a0 = __fmaf_rn(q4.w, v0.w, a0);
                a1 = __fmaf_rn(q4.x, v1.x, a1); a1 = __fmaf_rn(q4.y, v1.y, a1);
                a1 = __fmaf_rn(q4.z, v1.z, a1); a1 = __fmaf_rn(q4.w, v1.w, a1);
                a2 = __fmaf_rn(q4.x, v2.x, a2); a2 = __fmaf_rn(q4.y, v2.y, a2);
                a2 = __fmaf_rn(q4.z, v2.z, a2); a2 = __fmaf_rn(q4.w, v2.w, a2);
                a3 = __fmaf_rn(q4.x, v3.x, a3); a3 = __fmaf_rn(q4.y, v3.y, a3);
                a3 = __fmaf_rn(q4.z, v3.z, a3); a3 = __fmaf_rn(q4.w, v3.w, a3);
            }
            float d;
            d = __fadd_rn(__fsub_rn(q2, __fmul_rn(2.f, a0)), sn[c + 0]);
            if (d < best) { best = d; bi = c0 + cb + c + 0; }
            d = __fadd_rn(__fsub_rn(q2, __fmul_rn(2.f, a1)), sn[c + 1]);
            if (d < best) { best = d; bi = c0 + cb + c + 1; }
            d = __fadd_rn(__fsub_rn(q2, __fmul_rn(2.f, a2)), sn[c + 2]);
            if (d < best) { best = d; bi = c0 + cb + c + 2; }
            d = __fadd_rn(__fsub_rn(q2, __fmul_rn(2.f, a3)), sn[c + 3]);
            if (d < best) { best = d; bi = c0 + cb + c + 3; }
        }
    }
    pd[(size_t)q * G + blockIdx.y] = best;
    pi[(size_t)q * G + blockIdx.y] = bi;
}

__global__ void k_reduce(const float* __restrict__ pd, const int* __restrict__ pi,
                         int G, int NQ, int* __restrict__ out)
{
    int q = blockIdx.x * blockDim.x + threadIdx.x;
    if (q >= NQ) return;
    float best = 3.4e38f; int bi = 0;
    for (int g = 0; g < G; ++g) {
        float d = pd[(size_t)q * G + g];
        if (d < best) { best = d; bi = pi[(size_t)q * G + g]; }
    }
    out[q] = bi;
}

__global__ void k_gather(const float* __restrict__ src, const int* __restrict__ idx,
                         float* __restrict__ dst, int nsrc)
{
    int r = blockIdx.x, z = threadIdx.x;
    int i = idx[r];
    i = i < 0 ? 0 : (i >= nsrc ? nsrc - 1 : i);
    dst[(size_t)r * 64 + z] = src[(size_t)i * 64 + z];
}

// numpy pairwise row norm^2 (n=64), bit-exact.
__global__ void k_norm2(const float* __restrict__ s, float* __restrict__ o, int rows)
{
    int r0 = blockIdx.x * blockDim.x + threadIdx.x;
    if (r0 >= rows) return;
    const float* p = s + (size_t)r0 * 64;
    float r[8];
#pragma unroll
    for (int j = 0; j < 8; ++j) r[j] = __fmul_rn(p[j], p[j]);
#pragma unroll
    for (int i = 8; i < 64; i += 8)
#pragma unroll
        for (int j = 0; j < 8; ++j)
            r[j] = __fadd_rn(r[j], __fmul_rn(p[i + j], p[i + j]));
    float t01 = __fadd_rn(r[0], r[1]), t23 = __fadd_rn(r[2], r[3]);
    float t45 = __fadd_rn(r[4], r[5]), t67 = __fadd_rn(r[6], r[7]);
    o[r0] = __fadd_rn(__fadd_rn(t01, t23), __fadd_rn(t45, t67));
}

extern "C" void kernel_launch(void* const* d_in, const int* in_sizes, int n_in,
                              void* d_out, int out_size, void* d_ws, size_t ws_size,
                              hipStream_t stream)
{
    const int B  = 16384;
    const int KC = 4096;

    const float* X   = (const float*)d_in[0];
    const float* We1 = (const float*)d_in[1];
    const float* be1 = (const float*)d_in[2];
    const float* We2 = (const float*)d_in[3];
    const float* be2 = (const float*)d_in[4];
    const float* We3 = (const float*)d_in[5];
    const float* be3 = (const float*)d_in[6];
    const float* We4 = (const float*)d_in[7];
    const float* be4 = (const float*)d_in[8];
    const float* emb = (const float*)d_in[9];
    const float* Wd1 = (const float*)d_in[10];
    const float* bd1 = (const float*)d_in[11];
    const float* Wd2 = (const float*)d_in[12];
    const float* bd2 = (const float*)d_in[13];
    const float* Wd3 = (const float*)d_in[14];
    const float* bd3 = (const float*)d_in[15];
    const float* Wd4 = (const float*)d_in[16];
    const float* bd4 = (const float*)d_in[17];

    float* out = (float*)d_out;
    const size_t OFF1 = (size_t)B * 784;
    const size_t OFF2 = OFF1 + (size_t)B * 64;
    const size_t OFF3 = OFF2 + (size_t)B * 784;
    float* zenc = out + OFF1;

    // dynamic batch tiling: pick the largest MQ the workspace can hold
    // (ws_size is constant across calls -> same branch every call, graph-safe)
    const size_t FIXED = (size_t)12 << 20;   // pd/pi/zemb/small + margin
    int MQ;
    if      (ws_size >= FIXED + (size_t)16384 * 7200) MQ = 16384;
    else if (ws_size >= FIXED + (size_t)8192  * 7200) MQ = 8192;
    else                                              MQ = 4096;
    const int NQn = B / MQ;

    char* ws = (char*)d_ws;
    size_t off = 0;
    auto alloc = [&](size_t bytes) -> void* {
        void* p = ws + off;
        off = (off + bytes + 255) & ~(size_t)255;
        return p;
    };
    float* pd    = (float*)alloc((size_t)262144 * 4);
    int*   pi    = (int*)alloc((size_t)262144 * 4);
    int*   idx1  = (int*)alloc((size_t)B * 4);
    int*   idx2  = (int*)alloc((size_t)KC * 4);
    float* e2    = (float*)alloc((size_t)KC * 4);
    float* z2    = (float*)alloc((size_t)B * 4);
    float* zemb  = (float*)alloc((size_t)B * 64 * 4);
    float* h1    = (float*)alloc((size_t)MQ * 1000 * 4);
    float* h2    = (float*)alloc((size_t)MQ * 500 * 4);
    float* h3    = (float*)alloc((size_t)MQ * 300 * 4);
    float* d1f   = h3;
    float* d2f   = h2;
    float* d3f   = h1;

    dim3 blk(256);
    // encoder grids: layer1 RB=2 (128-row tile), layers 2-4 RB=1 (64-row)
    const dim3 eg1(8, MQ / 128), eg2(4, MQ / 64), eg3(3, MQ / 64), eg4(1, MQ / 64);
    // decoder grids (BM=128)
    const dim3 dq1(3, MQ / 128), dq2(4, MQ / 128), dq3(8, MQ / 128), dq4(7, MQ / 128);

    // ---- encoder, np-exact f32 (BLAS-order FMA chains) ----
    for (int q = 0; q < NQn; ++q) {
        const float* Xq = X + (size_t)q * MQ * 784;
        np_gemm<1, 2><<<eg1, blk, 0, stream>>>(Xq, We1, be1, h1, 1000, 784);
        np_gemm<1, 1><<<eg2, blk, 0, stream>>>(h1, We2, be2, h2, 500, 1000);
        np_gemm<1, 1><<<eg3, blk, 0, stream>>>(h2, We3, be3, h3, 300, 500);
        np_gemm<0, 1><<<eg4, blk, 0, stream>>>(h3, We4, be4,
                                               zenc + (size_t)q * MQ * 64, 64, 300);
    }

    // ---- nearest-neighbor: np-exact, no refine ----
    k_norm2<<<dim3((KC + 255) / 256), blk, 0, stream>>>(emb, e2, KC);
    k_norm2<<<dim3((B + 255) / 256),  blk, 0, stream>>>(zenc, z2, B);

    k_nearest<<<dim3(64, 16), blk, 0, stream>>>(zenc, emb, z2, e2, 256, pd, pi);
    k_reduce <<<dim3(B / 256), blk, 0, stream>>>(pd, pi, 16, B, idx1);
    k_gather <<<dim3(B), dim3(64), 0, stream>>>(emb, idx1, zemb, KC);

    k_nearest<<<dim3(16, 64), blk, 0, stream>>>(emb, zenc, e2, z2, 256, pd, pi);
    k_reduce <<<dim3(KC / 256), blk, 0, stream>>>(pd, pi, 64, KC, idx2);
    k_gather <<<dim3(KC), dim3(64), 0, stream>>>(zenc, idx2, out + OFF3, B);

    // ---- decoder; TERMS=2 bf16-split MFMA (4e-3 slack) ----
    for (int q = 0; q < NQn; ++q) {
        const float* zq = zemb + (size_t)q * MQ * 64;
        gemm_bt<2, 2><<<dq1, blk, 0, stream>>>(zq,  Wd1, bd1, d1f, nullptr, 300,  64);
        gemm_bt<2, 2><<<dq2, blk, 0, stream>>>(d1f, Wd2, bd2, d2f, nullptr, 500,  300);
        gemm_bt<2, 2><<<dq3, blk, 0, stream>>>(d2f, Wd3, bd3, d3f, nullptr, 1000, 500);
        gemm_bt<3, 2><<<dq4, blk, 0, stream>>>(d3f, Wd4, bd4,
                                               out + (size_t)q * MQ * 784,
                                               out + OFF2 + (size_t)q * MQ * 784, 784, 1000);
    }

    (void)in_sizes; (void)n_in; (void)out_size;
}